// Round 1
// baseline (411.172 us; speedup 1.0000x reference)
//
#include <hip/hip_runtime.h>
#include <stdint.h>

// VectorQuantizer: z [32768,64], codebook [1024,64] (dtype sniffed bf16/f32).
// d_out FLOAT32: z_q_st [2097152] ++ loss [1] ++ indices [32768].
// Bit-exact replication of the reference f32 arithmetic (numpy pairwise sums,
// sequential non-fused dot, f32 final adds, first-index argmin).
//
// R4 change vs R3 (300us vq_kernel, VALUBusy 27.6%, Occupancy 18.8%):
// latency-bound at 512 blocks (2 blocks/CU). Now 2048 blocks (16 rows x 16
// slices of 64 codes), 4-way ILP unroll of the code loop, cc[] + dtype sniff
// hoisted to a precompute kernel, exact-f64 loss only for final winners.
#define N_ROWS 32768
#define DIM 64
#define K_CODES 1024
#define ROWS_PER_BLOCK 16
#define SLICES 16
#define CODES_PER_SLICE (K_CODES / SLICES)   // 64
#define NBLOCKS (N_ROWS / ROWS_PER_BLOCK)    // 2048
#define N_ELEMS (N_ROWS * DIM)               // 2097152

// workspace layout (bytes):
// [0,4096)      float cc[1024]
// [4096,4100)   int flags  (bit0: z is bf16, bit1: cb is bf16)
// [8192,24576)  double partials[NBLOCKS]

__device__ __forceinline__ float bfbits(uint32_t b) { return __uint_as_float(b << 16); }

// round f32 -> nearest bf16 value, returned AS f32 (RNE; finite inputs)
__device__ __forceinline__ float round_bf16(float f) {
  uint32_t u = __float_as_uint(f);
  uint32_t r = ((u + 0x7FFFu + ((u >> 16) & 1u)) >> 16) << 16;
  return __uint_as_float(r);
}

// numpy pairwise_sum for n=64 (8 accumulators, 8 rounds, numpy's combine tree).
template <typename F>
__device__ __forceinline__ float np_sum64(F get) {
  float r0 = get(0), r1 = get(1), r2 = get(2), r3 = get(3);
  float r4 = get(4), r5 = get(5), r6 = get(6), r7 = get(7);
  for (int i = 8; i < 64; i += 8) {
    r0 = __fadd_rn(r0, get(i + 0)); r1 = __fadd_rn(r1, get(i + 1));
    r2 = __fadd_rn(r2, get(i + 2)); r3 = __fadd_rn(r3, get(i + 3));
    r4 = __fadd_rn(r4, get(i + 4)); r5 = __fadd_rn(r5, get(i + 5));
    r6 = __fadd_rn(r6, get(i + 6)); r7 = __fadd_rn(r7, get(i + 7));
  }
  return __fadd_rn(__fadd_rn(__fadd_rn(r0, r1), __fadd_rn(r2, r3)),
                   __fadd_rn(__fadd_rn(r4, r5), __fadd_rn(r6, r7)));
}

// Precompute: dtype sniff (block 0 writes flags) + cc_k = np.sum(c*c) per code.
__global__ __launch_bounds__(256) void vq_prep_kernel(
    const void* __restrict__ z, const void* __restrict__ cb,
    float* __restrict__ cc_out, int* __restrict__ flags) {
  const int tid = threadIdx.x;
  __shared__ int s_cnt[2];
  if (tid < 2) s_cnt[tid] = 0;
  __syncthreads();
  if (tid < 128) {
    uint32_t wc = ((const uint32_t*)cb)[(size_t)tid * 255];
    float vc = fabsf(bfbits(wc & 0xFFFFu));
    if (vc == 0.0f || (vc > 5.9e-8f && vc < 32.0f)) atomicAdd(&s_cnt[1], 1);
    if (blockIdx.x == 0) {
      uint32_t wz = ((const uint32_t*)z)[(size_t)tid * 8191];
      float vz = fabsf(bfbits(wz & 0xFFFFu));
      if (vz == 0.0f || (vz > 5.9e-8f && vz < 32.0f)) atomicAdd(&s_cnt[0], 1);
    }
  }
  __syncthreads();
  const bool cb_bf16 = s_cnt[1] >= 96;
  if (blockIdx.x == 0 && tid == 0)
    flags[0] = (s_cnt[0] >= 96 ? 1 : 0) | (cb_bf16 ? 2 : 0);

  const int kk = blockIdx.x * 256 + tid;
  float v;
  if (cb_bf16) {
    const uint16_t* cp = (const uint16_t*)cb + (size_t)kk * DIM;
    v = np_sum64([&](int d) { float c = bfbits((uint32_t)cp[d]);
                              return __fmul_rn(c, c); });
  } else {
    const float* cp = (const float*)cb + (size_t)kk * DIM;
    v = np_sum64([&](int d) { return __fmul_rn(cp[d], cp[d]); });
  }
  cc_out[kk] = v;
}

// Thread = (row r = tid&15, slice = tid>>4); each thread scans 64 codes.
__global__ __launch_bounds__(256, 4) void vq_kernel(
    const void* __restrict__ z, const void* __restrict__ cb,
    const float* __restrict__ cc_in, const int* __restrict__ flags,
    float* __restrict__ out, double* __restrict__ partials) {
  const int tid = threadIdx.x;
  const int fl = flags[0];
  const bool z_bf16  = (fl & 1) != 0;
  const bool cb_bf16 = (fl & 2) != 0;

  __shared__ float s_cc[K_CODES];
  #pragma unroll
  for (int kk = tid; kk < K_CODES; kk += 256) s_cc[kk] = cc_in[kk];

  const int r = tid & 15;
  const int slice = tid >> 4;
  const size_t row = (size_t)blockIdx.x * ROWS_PER_BLOCK + r;

  // Load z row as exact f32 values.
  float zf[DIM];
  if (z_bf16) {
    const uint16_t* p = (const uint16_t*)z + row * DIM;
    #pragma unroll
    for (int d = 0; d < DIM; ++d) zf[d] = bfbits((uint32_t)p[d]);
  } else {
    const float* p = (const float*)z + row * DIM;
    #pragma unroll
    for (int d = 0; d < DIM; ++d) zf[d] = p[d];
  }
  // zz = np.sum(z*z, axis=1) in f32, numpy pairwise order.
  const float zz = np_sum64([&](int d) { return __fmul_rn(zf[d], zf[d]); });

  __syncthreads();  // s_cc ready

  // Scan slice: d2 = fl(fl(zz + cc_k) - fl(2*g)), g = sequential f32 dot
  // (einsum inner loop, non-fused). argmin strict-< ascending k (np ties).
  // 4 codes in flight -> 4 independent fadd dependency chains.
  float best = 3.4e38f;
  int bk = 0;
  const int k0 = slice * CODES_PER_SLICE;
  if (cb_bf16) {
    for (int k = k0; k < k0 + CODES_PER_SLICE; k += 4) {
      const uint16_t* cp = (const uint16_t*)cb + (size_t)k * DIM;
      float g0 = 0.0f, g1 = 0.0f, g2 = 0.0f, g3 = 0.0f;
      #pragma unroll
      for (int d = 0; d < DIM; ++d) {
        g0 = __fadd_rn(g0, __fmul_rn(zf[d], bfbits((uint32_t)cp[d])));
        g1 = __fadd_rn(g1, __fmul_rn(zf[d], bfbits((uint32_t)cp[d + DIM])));
        g2 = __fadd_rn(g2, __fmul_rn(zf[d], bfbits((uint32_t)cp[d + 2 * DIM])));
        g3 = __fadd_rn(g3, __fmul_rn(zf[d], bfbits((uint32_t)cp[d + 3 * DIM])));
      }
      float e0 = __fsub_rn(__fadd_rn(zz, s_cc[k + 0]), __fmul_rn(2.0f, g0));
      float e1 = __fsub_rn(__fadd_rn(zz, s_cc[k + 1]), __fmul_rn(2.0f, g1));
      float e2 = __fsub_rn(__fadd_rn(zz, s_cc[k + 2]), __fmul_rn(2.0f, g2));
      float e3 = __fsub_rn(__fadd_rn(zz, s_cc[k + 3]), __fmul_rn(2.0f, g3));
      if (e0 < best) { best = e0; bk = k + 0; }
      if (e1 < best) { best = e1; bk = k + 1; }
      if (e2 < best) { best = e2; bk = k + 2; }
      if (e3 < best) { best = e3; bk = k + 3; }
    }
  } else {
    for (int k = k0; k < k0 + CODES_PER_SLICE; k += 4) {
      const float* cp = (const float*)cb + (size_t)k * DIM;
      float g0 = 0.0f, g1 = 0.0f, g2 = 0.0f, g3 = 0.0f;
      #pragma unroll
      for (int d = 0; d < DIM; ++d) {
        g0 = __fadd_rn(g0, __fmul_rn(zf[d], cp[d]));
        g1 = __fadd_rn(g1, __fmul_rn(zf[d], cp[d + DIM]));
        g2 = __fadd_rn(g2, __fmul_rn(zf[d], cp[d + 2 * DIM]));
        g3 = __fadd_rn(g3, __fmul_rn(zf[d], cp[d + 3 * DIM]));
      }
      float e0 = __fsub_rn(__fadd_rn(zz, s_cc[k + 0]), __fmul_rn(2.0f, g0));
      float e1 = __fsub_rn(__fadd_rn(zz, s_cc[k + 1]), __fmul_rn(2.0f, g1));
      float e2 = __fsub_rn(__fadd_rn(zz, s_cc[k + 2]), __fmul_rn(2.0f, g2));
      float e3 = __fsub_rn(__fadd_rn(zz, s_cc[k + 3]), __fmul_rn(2.0f, g3));
      if (e0 < best) { best = e0; bk = k + 0; }
      if (e1 < best) { best = e1; bk = k + 1; }
      if (e2 < best) { best = e2; bk = k + 2; }
      if (e3 < best) { best = e3; bk = k + 3; }
    }
  }

  __shared__ float s_best[256];
  __shared__ int s_k[256];
  __shared__ int s_win[ROWS_PER_BLOCK];
  __shared__ double s_loss[ROWS_PER_BLOCK];
  s_best[tid] = best;
  s_k[tid] = bk;
  __syncthreads();

  if (tid < ROWS_PER_BLOCK) {
    // Combine slices ascending with strict < -> global first-index tie-break.
    float b = s_best[tid];
    int bbk = s_k[tid];
    for (int s2 = 1; s2 < SLICES; ++s2) {
      float v = s_best[s2 * ROWS_PER_BLOCK + tid];
      if (v < b) { b = v; bbk = s_k[s2 * ROWS_PER_BLOCK + tid]; }
    }
    s_win[tid] = bbk;
    // Exact squared distance of the winner (fp64) — this thread owns row tid's zf.
    double acc = 0.0;
    if (cb_bf16) {
      const uint16_t* cp = (const uint16_t*)cb + (size_t)bbk * DIM;
      for (int d = 0; d < DIM; ++d) {
        double df = (double)zf[d] - (double)bfbits((uint32_t)cp[d]);
        acc = fma(df, df, acc);
      }
    } else {
      const float* cp = (const float*)cb + (size_t)bbk * DIM;
      for (int d = 0; d < DIM; ++d) {
        double df = (double)zf[d] - (double)cp[d];
        acc = fma(df, df, acc);
      }
    }
    s_loss[tid] = acc;
    const size_t myrow = (size_t)blockIdx.x * ROWS_PER_BLOCK + tid;
    out[(size_t)N_ELEMS + 1 + myrow] = round_bf16((float)bbk);
  }
  __syncthreads();

  // z_q write: 16 rows x 64 dims = 1024 floats, 256 threads x 4, coalesced.
  const size_t base = (size_t)blockIdx.x * ROWS_PER_BLOCK * DIM;
  #pragma unroll
  for (int j = 0; j < 4; ++j) {
    int idx = tid + 256 * j;
    int rr = idx >> 6, dd = idx & 63;
    int w = s_win[rr];
    float v;
    if (cb_bf16) v = bfbits((uint32_t)((const uint16_t*)cb)[(size_t)w * DIM + dd]);
    else         v = round_bf16(((const float*)cb)[(size_t)w * DIM + dd]);
    out[base + idx] = v;
  }

  if (tid == 0) {
    double s = 0.0;
    for (int i = 0; i < ROWS_PER_BLOCK; ++i) s += s_loss[i];
    partials[blockIdx.x] = s;
  }
}

__global__ __launch_bounds__(256) void vq_loss_kernel(
    const double* __restrict__ partials, float* __restrict__ out) {
  __shared__ double sh[256];
  const int tid = threadIdx.x;
  double s = 0.0;
  for (int i = tid; i < NBLOCKS; i += 256) s += partials[i];
  sh[tid] = s;
  __syncthreads();
  if (tid == 0) {
    double t = 0.0;
    for (int i = 0; i < 256; ++i) t += sh[i];
    out[N_ELEMS] = round_bf16((float)(1.25 * t / (double)N_ELEMS));
  }
}

extern "C" void kernel_launch(void* const* d_in, const int* in_sizes, int n_in,
                              void* d_out, int out_size, void* d_ws, size_t ws_size,
                              hipStream_t stream) {
  const void* z  = d_in[0];
  const void* cb = d_in[1];
  float* out = (float*)d_out;
  uint8_t* ws = (uint8_t*)d_ws;
  float* cc = (float*)ws;
  int* flags = (int*)(ws + 4096);
  double* partials = (double*)(ws + 8192);

  vq_prep_kernel<<<K_CODES / 256, 256, 0, stream>>>(z, cb, cc, flags);
  vq_kernel<<<NBLOCKS, 256, 0, stream>>>(z, cb, cc, flags, out, partials);
  vq_loss_kernel<<<1, 256, 0, stream>>>(partials, out);
}

// Round 2
// 318.092 us; speedup vs baseline: 1.2926x; 1.2926x over previous
//
#include <hip/hip_runtime.h>
#include <stdint.h>

// VectorQuantizer: z [32768,64], codebook [1024,64] (dtype sniffed bf16/f32).
// d_out FLOAT32: z_q_st [2097152] ++ loss [1] ++ indices [32768].
// Bit-exact replication of the reference f32 arithmetic (numpy pairwise sums,
// sequential non-fused dot, f32 final adds, first-index argmin).
//
// R5 vs R4 (411us, VGPR 64, 66MB writes): __launch_bounds__(256,4) let the
// allocator chase 8 waves/EU and SPILL zf[64] to scratch. Drop the min-waves
// arg (natural ~90-120 VGPR, no spill), grid 1024 blocks (32 rows x 8 slices
// of 128 codes) = 4 blocks/CU residency, keep the 4-way ILP code loop.
#define N_ROWS 32768
#define DIM 64
#define K_CODES 1024
#define ROWS_PER_BLOCK 32
#define SLICES 8
#define CODES_PER_SLICE (K_CODES / SLICES)   // 128
#define NBLOCKS (N_ROWS / ROWS_PER_BLOCK)    // 1024
#define N_ELEMS (N_ROWS * DIM)               // 2097152

// workspace layout (bytes):
// [0,4096)      float cc[1024]
// [4096,4100)   int flags  (bit0: z is bf16, bit1: cb is bf16)
// [8192,8192+NBLOCKS*8)  double partials[NBLOCKS]

__device__ __forceinline__ float bfbits(uint32_t b) { return __uint_as_float(b << 16); }

// round f32 -> nearest bf16 value, returned AS f32 (RNE; finite inputs)
__device__ __forceinline__ float round_bf16(float f) {
  uint32_t u = __float_as_uint(f);
  uint32_t r = ((u + 0x7FFFu + ((u >> 16) & 1u)) >> 16) << 16;
  return __uint_as_float(r);
}

// numpy pairwise_sum for n=64 (8 accumulators, 8 rounds, numpy's combine tree).
template <typename F>
__device__ __forceinline__ float np_sum64(F get) {
  float r0 = get(0), r1 = get(1), r2 = get(2), r3 = get(3);
  float r4 = get(4), r5 = get(5), r6 = get(6), r7 = get(7);
  for (int i = 8; i < 64; i += 8) {
    r0 = __fadd_rn(r0, get(i + 0)); r1 = __fadd_rn(r1, get(i + 1));
    r2 = __fadd_rn(r2, get(i + 2)); r3 = __fadd_rn(r3, get(i + 3));
    r4 = __fadd_rn(r4, get(i + 4)); r5 = __fadd_rn(r5, get(i + 5));
    r6 = __fadd_rn(r6, get(i + 6)); r7 = __fadd_rn(r7, get(i + 7));
  }
  return __fadd_rn(__fadd_rn(__fadd_rn(r0, r1), __fadd_rn(r2, r3)),
                   __fadd_rn(__fadd_rn(r4, r5), __fadd_rn(r6, r7)));
}

// Precompute: dtype sniff (block 0 writes flags) + cc_k = np.sum(c*c) per code.
__global__ __launch_bounds__(256) void vq_prep_kernel(
    const void* __restrict__ z, const void* __restrict__ cb,
    float* __restrict__ cc_out, int* __restrict__ flags) {
  const int tid = threadIdx.x;
  __shared__ int s_cnt[2];
  if (tid < 2) s_cnt[tid] = 0;
  __syncthreads();
  if (tid < 128) {
    uint32_t wc = ((const uint32_t*)cb)[(size_t)tid * 255];
    float vc = fabsf(bfbits(wc & 0xFFFFu));
    if (vc == 0.0f || (vc > 5.9e-8f && vc < 32.0f)) atomicAdd(&s_cnt[1], 1);
    if (blockIdx.x == 0) {
      uint32_t wz = ((const uint32_t*)z)[(size_t)tid * 8191];
      float vz = fabsf(bfbits(wz & 0xFFFFu));
      if (vz == 0.0f || (vz > 5.9e-8f && vz < 32.0f)) atomicAdd(&s_cnt[0], 1);
    }
  }
  __syncthreads();
  const bool cb_bf16 = s_cnt[1] >= 96;
  if (blockIdx.x == 0 && tid == 0)
    flags[0] = (s_cnt[0] >= 96 ? 1 : 0) | (cb_bf16 ? 2 : 0);

  const int kk = blockIdx.x * 256 + tid;
  float v;
  if (cb_bf16) {
    const uint16_t* cp = (const uint16_t*)cb + (size_t)kk * DIM;
    v = np_sum64([&](int d) { float c = bfbits((uint32_t)cp[d]);
                              return __fmul_rn(c, c); });
  } else {
    const float* cp = (const float*)cb + (size_t)kk * DIM;
    v = np_sum64([&](int d) { return __fmul_rn(cp[d], cp[d]); });
  }
  cc_out[kk] = v;
}

// Thread = (row r = tid&31, slice = tid>>5); each thread scans 128 codes.
__global__ __launch_bounds__(256) void vq_kernel(
    const void* __restrict__ z, const void* __restrict__ cb,
    const float* __restrict__ cc_in, const int* __restrict__ flags,
    float* __restrict__ out, double* __restrict__ partials) {
  const int tid = threadIdx.x;
  const int fl = flags[0];
  const bool z_bf16  = (fl & 1) != 0;
  const bool cb_bf16 = (fl & 2) != 0;

  __shared__ float s_cc[K_CODES];
  #pragma unroll
  for (int kk = tid; kk < K_CODES; kk += 256) s_cc[kk] = cc_in[kk];

  const int r = tid & (ROWS_PER_BLOCK - 1);
  const int slice = tid >> 5;
  const size_t row = (size_t)blockIdx.x * ROWS_PER_BLOCK + r;

  // Load z row as exact f32 values.
  float zf[DIM];
  if (z_bf16) {
    const uint16_t* p = (const uint16_t*)z + row * DIM;
    #pragma unroll
    for (int d = 0; d < DIM; ++d) zf[d] = bfbits((uint32_t)p[d]);
  } else {
    const float* p = (const float*)z + row * DIM;
    #pragma unroll
    for (int d = 0; d < DIM; ++d) zf[d] = p[d];
  }
  // zz = np.sum(z*z, axis=1) in f32, numpy pairwise order.
  const float zz = np_sum64([&](int d) { return __fmul_rn(zf[d], zf[d]); });

  __syncthreads();  // s_cc ready

  // Scan slice: d2 = fl(fl(zz + cc_k) - fl(2*g)), g = sequential f32 dot
  // (einsum inner loop, non-fused). argmin strict-< ascending k (np ties).
  // 4 codes in flight -> 4 independent fadd dependency chains.
  float best = 3.4e38f;
  int bk = 0;
  const int k0 = slice * CODES_PER_SLICE;
  if (cb_bf16) {
    for (int k = k0; k < k0 + CODES_PER_SLICE; k += 4) {
      const uint16_t* cp = (const uint16_t*)cb + (size_t)k * DIM;
      float g0 = 0.0f, g1 = 0.0f, g2 = 0.0f, g3 = 0.0f;
      #pragma unroll
      for (int d = 0; d < DIM; ++d) {
        g0 = __fadd_rn(g0, __fmul_rn(zf[d], bfbits((uint32_t)cp[d])));
        g1 = __fadd_rn(g1, __fmul_rn(zf[d], bfbits((uint32_t)cp[d + DIM])));
        g2 = __fadd_rn(g2, __fmul_rn(zf[d], bfbits((uint32_t)cp[d + 2 * DIM])));
        g3 = __fadd_rn(g3, __fmul_rn(zf[d], bfbits((uint32_t)cp[d + 3 * DIM])));
      }
      float e0 = __fsub_rn(__fadd_rn(zz, s_cc[k + 0]), __fmul_rn(2.0f, g0));
      float e1 = __fsub_rn(__fadd_rn(zz, s_cc[k + 1]), __fmul_rn(2.0f, g1));
      float e2 = __fsub_rn(__fadd_rn(zz, s_cc[k + 2]), __fmul_rn(2.0f, g2));
      float e3 = __fsub_rn(__fadd_rn(zz, s_cc[k + 3]), __fmul_rn(2.0f, g3));
      if (e0 < best) { best = e0; bk = k + 0; }
      if (e1 < best) { best = e1; bk = k + 1; }
      if (e2 < best) { best = e2; bk = k + 2; }
      if (e3 < best) { best = e3; bk = k + 3; }
    }
  } else {
    for (int k = k0; k < k0 + CODES_PER_SLICE; k += 4) {
      const float* cp = (const float*)cb + (size_t)k * DIM;
      float g0 = 0.0f, g1 = 0.0f, g2 = 0.0f, g3 = 0.0f;
      #pragma unroll
      for (int d = 0; d < DIM; ++d) {
        g0 = __fadd_rn(g0, __fmul_rn(zf[d], cp[d]));
        g1 = __fadd_rn(g1, __fmul_rn(zf[d], cp[d + DIM]));
        g2 = __fadd_rn(g2, __fmul_rn(zf[d], cp[d + 2 * DIM]));
        g3 = __fadd_rn(g3, __fmul_rn(zf[d], cp[d + 3 * DIM]));
      }
      float e0 = __fsub_rn(__fadd_rn(zz, s_cc[k + 0]), __fmul_rn(2.0f, g0));
      float e1 = __fsub_rn(__fadd_rn(zz, s_cc[k + 1]), __fmul_rn(2.0f, g1));
      float e2 = __fsub_rn(__fadd_rn(zz, s_cc[k + 2]), __fmul_rn(2.0f, g2));
      float e3 = __fsub_rn(__fadd_rn(zz, s_cc[k + 3]), __fmul_rn(2.0f, g3));
      if (e0 < best) { best = e0; bk = k + 0; }
      if (e1 < best) { best = e1; bk = k + 1; }
      if (e2 < best) { best = e2; bk = k + 2; }
      if (e3 < best) { best = e3; bk = k + 3; }
    }
  }

  __shared__ float s_best[256];
  __shared__ int s_k[256];
  __shared__ int s_win[ROWS_PER_BLOCK];
  __shared__ double s_loss[ROWS_PER_BLOCK];
  s_best[tid] = best;
  s_k[tid] = bk;
  __syncthreads();

  if (tid < ROWS_PER_BLOCK) {
    // Combine slices ascending with strict < -> global first-index tie-break.
    float b = s_best[tid];
    int bbk = s_k[tid];
    for (int s2 = 1; s2 < SLICES; ++s2) {
      float v = s_best[s2 * ROWS_PER_BLOCK + tid];
      if (v < b) { b = v; bbk = s_k[s2 * ROWS_PER_BLOCK + tid]; }
    }
    s_win[tid] = bbk;
    // Exact squared distance of the winner (fp64) — this thread owns row tid's zf.
    double acc = 0.0;
    if (cb_bf16) {
      const uint16_t* cp = (const uint16_t*)cb + (size_t)bbk * DIM;
      for (int d = 0; d < DIM; ++d) {
        double df = (double)zf[d] - (double)bfbits((uint32_t)cp[d]);
        acc = fma(df, df, acc);
      }
    } else {
      const float* cp = (const float*)cb + (size_t)bbk * DIM;
      for (int d = 0; d < DIM; ++d) {
        double df = (double)zf[d] - (double)cp[d];
        acc = fma(df, df, acc);
      }
    }
    s_loss[tid] = acc;
    const size_t myrow = (size_t)blockIdx.x * ROWS_PER_BLOCK + tid;
    out[(size_t)N_ELEMS + 1 + myrow] = round_bf16((float)bbk);
  }
  __syncthreads();

  // z_q write: 32 rows x 64 dims = 2048 floats, 256 threads x 8, coalesced.
  const size_t base = (size_t)blockIdx.x * ROWS_PER_BLOCK * DIM;
  #pragma unroll
  for (int j = 0; j < 8; ++j) {
    int idx = tid + 256 * j;
    int rr = idx >> 6, dd = idx & 63;
    int w = s_win[rr];
    float v;
    if (cb_bf16) v = bfbits((uint32_t)((const uint16_t*)cb)[(size_t)w * DIM + dd]);
    else         v = round_bf16(((const float*)cb)[(size_t)w * DIM + dd]);
    out[base + idx] = v;
  }

  if (tid == 0) {
    double s = 0.0;
    for (int i = 0; i < ROWS_PER_BLOCK; ++i) s += s_loss[i];
    partials[blockIdx.x] = s;
  }
}

__global__ __launch_bounds__(256) void vq_loss_kernel(
    const double* __restrict__ partials, float* __restrict__ out) {
  __shared__ double sh[256];
  const int tid = threadIdx.x;
  double s = 0.0;
  for (int i = tid; i < NBLOCKS; i += 256) s += partials[i];
  sh[tid] = s;
  __syncthreads();
  if (tid == 0) {
    double t = 0.0;
    for (int i = 0; i < 256; ++i) t += sh[i];
    out[N_ELEMS] = round_bf16((float)(1.25 * t / (double)N_ELEMS));
  }
}

extern "C" void kernel_launch(void* const* d_in, const int* in_sizes, int n_in,
                              void* d_out, int out_size, void* d_ws, size_t ws_size,
                              hipStream_t stream) {
  const void* z  = d_in[0];
  const void* cb = d_in[1];
  float* out = (float*)d_out;
  uint8_t* ws = (uint8_t*)d_ws;
  float* cc = (float*)ws;
  int* flags = (int*)(ws + 4096);
  double* partials = (double*)(ws + 8192);

  vq_prep_kernel<<<K_CODES / 256, 256, 0, stream>>>(z, cb, cc, flags);
  vq_kernel<<<NBLOCKS, 256, 0, stream>>>(z, cb, cc, flags, out, partials);
  vq_loss_kernel<<<1, 256, 0, stream>>>(partials, out);
}